// Round 5
// baseline (308.531 us; speedup 1.0000x reference)
//
#include <hip/hip_runtime.h>
#include <math.h>

#define B_SZ 2048
#define DIN  1024
#define H_SZ 4096
#define D_SZ 128
#define P_SZ 1000

typedef __attribute__((ext_vector_type(8))) short bf16x8;
typedef __attribute__((ext_vector_type(4))) float f32x4;

__device__ __forceinline__ float gelu_exact(float v) {
    return 0.5f * v * (1.0f + erff(v * 0.70710678118654752f));
}

__device__ __forceinline__ short f2bf(float f) {
    unsigned u = __float_as_uint(f);
    u = (u + 0x7fffu + ((u >> 16) & 1u)) >> 16;
    return (short)u;
}

// async global->LDS, 16B per lane. LDS dest = wave-uniform base + lane*16.
__device__ __forceinline__ void gload_lds16(const void* g, void* l) {
    __builtin_amdgcn_global_load_lds(
        (__attribute__((address_space(1))) void*)(uintptr_t)g,
        (__attribute__((address_space(3))) void*)(uintptr_t)l,
        16, 0, 0);
}

// ---------------------------------------------------------------------------
// fp32 -> bf16 elementwise
// ---------------------------------------------------------------------------
__global__ __launch_bounds__(256) void cvt_bf16(
    const float* __restrict__ in, short* __restrict__ out, int n)
{
    const int i = (blockIdx.x * 256 + threadIdx.x) * 4;
    if (i + 3 < n) {
        const float4 v = *reinterpret_cast<const float4*>(&in[i]);
        short4 o;
        o.x = f2bf(v.x); o.y = f2bf(v.y); o.z = f2bf(v.z); o.w = f2bf(v.w);
        *reinterpret_cast<short4*>(&out[i]) = o;
    }
}

// ---------------------------------------------------------------------------
// Transpose + convert: W[K][N] fp32 -> WT[N][K] bf16. 64x64 tiles.
// ---------------------------------------------------------------------------
__global__ __launch_bounds__(256) void transpose_bf16(
    const float* __restrict__ W, short* __restrict__ WT, int K, int N)
{
    __shared__ float t[64][65];
    const int tid = threadIdx.x;
    const int tx = tid & 63, ty = tid >> 6;
    const int n0 = blockIdx.x * 64, k0 = blockIdx.y * 64;
    #pragma unroll
    for (int r = 0; r < 64; r += 4)
        t[r + ty][tx] = W[(size_t)(k0 + r + ty) * N + n0 + tx];
    __syncthreads();
    #pragma unroll
    for (int r = 0; r < 64; r += 4)
        WT[(size_t)(n0 + r + ty) * K + k0 + tx] = f2bf(t[tx][r + ty]);
}

// ---------------------------------------------------------------------------
// Big pipelined bf16 MFMA GEMM: C = gelu(A @ B + bias) -> bf16
//   A : M x K bf16 row-major;  BT : N x K bf16 row-major (B transposed)
// Tile 256(M) x 128(N), BK=64, 512 threads = 8 waves (4M x 2N), per-wave 64x64.
// 3-deep LDS pipeline, counted vmcnt(6), 2 barrier-delimited phases per K-tile
// (T3+T4+T5), source-side XOR swizzle for conflict-free ds_read_b128 (T2),
// chunked XCD swizzle (T1; nwg % 8 == 0 here).
// ---------------------------------------------------------------------------
__global__ __launch_bounds__(512) void gemm_big(
    const short* __restrict__ A, const short* __restrict__ BT,
    const float* __restrict__ bias, short* __restrict__ Cout,
    int M, int N, int K)
{
    extern __shared__ __align__(16) char smem[];   // 3 * (32KB A + 16KB B)

    const int tid  = threadIdx.x;
    const int lane = tid & 63;
    const int wid  = tid >> 6;

    // chunked XCD swizzle: XCD c owns a contiguous chunk of the swizzled grid
    const int nwg = gridDim.x * gridDim.y;          // 256, divisible by 8
    const int bid = blockIdx.y * gridDim.x + blockIdx.x;
    const int swz = (bid & 7) * (nwg >> 3) + (bid >> 3);
    const int row0 = (swz / gridDim.x) * 256;
    const int col0 = (swz % gridDim.x) * 128;

    const int wm = (wid >> 1) * 64;    // wave's 64-row slab
    const int wn = (wid & 1) * 64;     // wave's 64-col slab
    const int lr = lane & 15, kq = lane >> 4;

    const int NT = K >> 6;             // K / 64 tiles

    f32x4 acc[4][4];
    #pragma unroll
    for (int i = 0; i < 4; ++i)
        #pragma unroll
        for (int j = 0; j < 4; ++j) acc[i][j] = (f32x4){0.f, 0.f, 0.f, 0.f};

    // per-lane staging source (pre-swizzled k-chunk)
    const int srow = lane >> 3;              // row within 8-row group
    const int kch  = (lane & 7) ^ srow;      // swizzled 16B k-chunk 0..7
    const short* Ag = A  + (size_t)(row0 + wid * 32 + srow) * K + kch * 8;
    const short* Bg = BT + (size_t)(col0 + wid * 16 + srow) * K + kch * 8;

    auto stage = [&](int t) {
        const int buf = t % 3;
        char* sA = smem + buf * 49152;
        char* sB = sA + 32768;
        const int k0 = t << 6;
        #pragma unroll
        for (int ii = 0; ii < 4; ++ii)      // A: 256 rows = 32 instr, 4/wave
            gload_lds16(Ag + (size_t)ii * 8 * K + k0, sA + (wid * 4 + ii) * 1024);
        #pragma unroll
        for (int ii = 0; ii < 2; ++ii)      // B: 128 rows = 16 instr, 2/wave
            gload_lds16(Bg + (size_t)ii * 8 * K + k0, sB + (wid * 2 + ii) * 1024);
    };

    auto read_frags = [&](const char* sA, const char* sB, int ks,
                          bf16x8* af, bf16x8* bfv) {
        #pragma unroll
        for (int i = 0; i < 4; ++i)
            af[i] = *reinterpret_cast<const bf16x8*>(
                sA + (wm + i * 16 + lr) * 128 + (((ks * 4 + kq) ^ (lr & 7)) * 16));
        #pragma unroll
        for (int j = 0; j < 4; ++j)
            bfv[j] = *reinterpret_cast<const bf16x8*>(
                sB + (wn + j * 16 + lr) * 128 + (((ks * 4 + kq) ^ (lr & 7)) * 16));
    };

    stage(0);
    stage(1);
    asm volatile("s_waitcnt vmcnt(6)" ::: "memory");   // tile 0 resident
    __builtin_amdgcn_s_barrier();
    asm volatile("" ::: "memory");

    for (int t = 0; t < NT; ++t) {
        const bool more = (t + 2) < NT;    // block-uniform
        const char* sA = smem + (t % 3) * 49152;
        const char* sB = sA + 32768;
        bf16x8 af[4], bfv[4];

        // ---- phase A (ks = 0): ds_read || stage-issue, then MFMA cluster
        read_frags(sA, sB, 0, af, bfv);
        if (more) stage(t + 2);
        asm volatile("" ::: "memory");
        __builtin_amdgcn_s_barrier();
        asm volatile("s_waitcnt lgkmcnt(0)" ::: "memory");
        __builtin_amdgcn_sched_barrier(0);
        __builtin_amdgcn_s_setprio(1);
        #pragma unroll
        for (int i = 0; i < 4; ++i)
            #pragma unroll
            for (int j = 0; j < 4; ++j)
                acc[i][j] = __builtin_amdgcn_mfma_f32_16x16x32_bf16(
                    af[i], bfv[j], acc[i][j], 0, 0, 0);
        __builtin_amdgcn_s_setprio(0);
        asm volatile("" ::: "memory");
        __builtin_amdgcn_s_barrier();

        // ---- phase B (ks = 1): ds_read, counted vmcnt for t+1 residency
        read_frags(sA, sB, 1, af, bfv);
        if (more) asm volatile("s_waitcnt vmcnt(6)" ::: "memory");
        else      asm volatile("s_waitcnt vmcnt(0)" ::: "memory");
        __builtin_amdgcn_s_barrier();
        asm volatile("s_waitcnt lgkmcnt(0)" ::: "memory");
        __builtin_amdgcn_sched_barrier(0);
        __builtin_amdgcn_s_setprio(1);
        #pragma unroll
        for (int i = 0; i < 4; ++i)
            #pragma unroll
            for (int j = 0; j < 4; ++j)
                acc[i][j] = __builtin_amdgcn_mfma_f32_16x16x32_bf16(
                    af[i], bfv[j], acc[i][j], 0, 0, 0);
        __builtin_amdgcn_s_setprio(0);
        asm volatile("" ::: "memory");
        __builtin_amdgcn_s_barrier();
    }

    // Epilogue. D frag layout: row = (lane>>4)*4 + q, col = lane&15.
    #pragma unroll
    for (int j = 0; j < 4; ++j) {
        const int col = col0 + wn + j * 16 + lr;
        const float bv = bias[col];
        #pragma unroll
        for (int i = 0; i < 4; ++i) {
            #pragma unroll
            for (int q = 0; q < 4; ++q) {
                const int row = row0 + wm + i * 16 + kq * 4 + q;
                float v = gelu_exact(acc[i][j][q] + bv);
                Cout[(size_t)row * N + col] = f2bf(v);
            }
        }
    }
}

// ---------------------------------------------------------------------------
// Small bf16 GEMM (split-K partial, fp32 atomicAdd) — for skinny GEMM3.
// ---------------------------------------------------------------------------
__global__ __launch_bounds__(256) void gemm_small_splitk(
    const short* __restrict__ A, const short* __restrict__ BT,
    float* __restrict__ Cout, int M, int N, int K)
{
    __shared__ __align__(16) short sA[4 * 128 * 8];
    __shared__ __align__(16) short sB[4 * 128 * 8];

    const int tid  = threadIdx.x;
    const int lane = tid & 63;
    const int wid  = tid >> 6;
    const int row0 = blockIdx.y * 128;
    const int col0 = blockIdx.x * 128;
    const int wm = (wid >> 1) * 64;
    const int wn = (wid & 1) * 64;

    const int kpb    = K / gridDim.z;
    const int kstart = blockIdx.z * kpb;

    f32x4 acc[4][4];
    #pragma unroll
    for (int i = 0; i < 4; ++i)
        #pragma unroll
        for (int j = 0; j < 4; ++j) acc[i][j] = (f32x4){0.f, 0.f, 0.f, 0.f};

    const short* Ab = A  + (size_t)(row0 + lane) * K;
    const short* Bb = BT + (size_t)(col0 + lane) * K;
    short* ldsA = &sA[wid * (128 * 8)];
    short* ldsB = &sB[wid * (128 * 8)];

    const int kq = lane >> 4;
    const int lr = lane & 15;

    for (int k0 = kstart; k0 < kstart + kpb; k0 += 32) {
        gload_lds16(Ab + k0 + wid * 8,                  ldsA);
        gload_lds16(Ab + (size_t)64 * K + k0 + wid * 8, ldsA + 64 * 8);
        gload_lds16(Bb + k0 + wid * 8,                  ldsB);
        gload_lds16(Bb + (size_t)64 * K + k0 + wid * 8, ldsB + 64 * 8);
        __syncthreads();

        bf16x8 af[4], bfr[4];
        #pragma unroll
        for (int i = 0; i < 4; ++i)
            af[i] = *reinterpret_cast<const bf16x8*>(&sA[kq * (128 * 8) + (wm + i * 16 + lr) * 8]);
        #pragma unroll
        for (int j = 0; j < 4; ++j)
            bfr[j] = *reinterpret_cast<const bf16x8*>(&sB[kq * (128 * 8) + (wn + j * 16 + lr) * 8]);

        #pragma unroll
        for (int i = 0; i < 4; ++i)
            #pragma unroll
            for (int j = 0; j < 4; ++j)
                acc[i][j] = __builtin_amdgcn_mfma_f32_16x16x32_bf16(af[i], bfr[j], acc[i][j], 0, 0, 0);
        __syncthreads();
    }

    #pragma unroll
    for (int j = 0; j < 4; ++j) {
        const int col = col0 + wn + j * 16 + lr;
        if (col < N) {
            #pragma unroll
            for (int i = 0; i < 4; ++i)
                #pragma unroll
                for (int q = 0; q < 4; ++q) {
                    const int row = row0 + wm + i * 16 + kq * 4 + q;
                    atomicAdd(&Cout[(size_t)row * N + col], acc[i][j][q]);
                }
        }
    }
}

// ---------------------------------------------------------------------------
// expmap0: u (in-place, fp32) -> x_hyp ; rowb2 = tanh(||u||)^2. Adds bias b3.
// ---------------------------------------------------------------------------
__global__ __launch_bounds__(128) void expmap_kernel(
    float* __restrict__ uxh, const float* __restrict__ b3, float* __restrict__ rowb2)
{
    const int b = blockIdx.x;
    const int d = threadIdx.x;
    float u = uxh[(size_t)b * D_SZ + d] + b3[d];

    float s = u * u;
    #pragma unroll
    for (int off = 32; off; off >>= 1) s += __shfl_down(s, off);
    __shared__ float part[2];
    if ((d & 63) == 0) part[d >> 6] = s;
    __syncthreads();
    const float n2 = part[0] + part[1];

    const float n = fmaxf(sqrtf(n2), 1e-15f);
    const float t = tanhf(n);
    uxh[(size_t)b * D_SZ + d] = u * (t / n);
    if (d == 0) rowb2[b] = t * t;
}

__global__ __launch_bounds__(128) void a2_kernel(
    const float* __restrict__ proto, float* __restrict__ a2g)
{
    const int p = blockIdx.x;
    const int d = threadIdx.x;
    const float y = proto[(size_t)p * D_SZ + d];
    float s = y * y;
    #pragma unroll
    for (int off = 32; off; off >>= 1) s += __shfl_down(s, off);
    __shared__ float part[2];
    if ((d & 63) == 0) part[d >> 6] = s;
    __syncthreads();
    if (d == 0) a2g[p] = part[0] + part[1];
}

// ---------------------------------------------------------------------------
// Pairwise hyperbolic distance -> logits (fp32). 64(b) x 64(p) per block.
// ---------------------------------------------------------------------------
__global__ __launch_bounds__(256) void dist_kernel(
    const float* __restrict__ xh, const float* __restrict__ proto,
    const float* __restrict__ rowb2, const float* __restrict__ a2g,
    float* __restrict__ logits)
{
    __shared__ float xs[128][68];
    __shared__ float ps[128][68];
    __shared__ float sb2[64], sa2[64];

    const int tid = threadIdx.x;
    const int pt = blockIdx.x * 64;
    const int bt = blockIdx.y * 64;

    #pragma unroll
    for (int r = 0; r < 8; ++r) {
        const int idx = r * 256 + tid;
        const int row = idx >> 5;
        const int dq  = (idx & 31) * 4;
        const float4 v = *reinterpret_cast<const float4*>(&xh[(size_t)(bt + row) * D_SZ + dq]);
        xs[dq + 0][row] = v.x; xs[dq + 1][row] = v.y; xs[dq + 2][row] = v.z; xs[dq + 3][row] = v.w;
        const int prow = pt + row;
        float4 w = {0.f, 0.f, 0.f, 0.f};
        if (prow < P_SZ) w = *reinterpret_cast<const float4*>(&proto[(size_t)prow * D_SZ + dq]);
        ps[dq + 0][row] = w.x; ps[dq + 1][row] = w.y; ps[dq + 2][row] = w.z; ps[dq + 3][row] = w.w;
    }
    if (tid < 64) {
        sb2[tid] = rowb2[bt + tid];
        sa2[tid] = (pt + tid < P_SZ) ? a2g[pt + tid] : 0.f;
    }
    __syncthreads();

    const int tx = tid & 15, ty = tid >> 4;
    float dot[4][4] = {};
    for (int d = 0; d < 128; ++d) {
        const float4 a4 = *reinterpret_cast<const float4*>(&xs[d][ty * 4]);
        const float4 b4 = *reinterpret_cast<const float4*>(&ps[d][tx * 4]);
        const float aa[4] = {a4.x, a4.y, a4.z, a4.w};
        const float bb[4] = {b4.x, b4.y, b4.z, b4.w};
        #pragma unroll
        for (int i = 0; i < 4; ++i)
            #pragma unroll
            for (int j = 0; j < 4; ++j)
                dot[i][j] = fmaf(aa[i], bb[j], dot[i][j]);
    }

    #pragma unroll
    for (int i = 0; i < 4; ++i) {
        const int b = bt + ty * 4 + i;
        const float b2 = sb2[ty * 4 + i];
        #pragma unroll
        for (int j = 0; j < 4; ++j) {
            const int p = pt + tx * 4 + j;
            if (p < P_SZ) {
                const float a2 = sa2[tx * 4 + j];
                const float ab = -dot[i][j];
                const float alpha = 1.f + 2.f * ab + b2;
                const float beta  = 1.f - a2;
                const float gamma = 1.f + 2.f * ab + a2 * b2;
                const float num = alpha * alpha * a2 + 2.f * alpha * beta * ab + beta * beta * b2;
                const float m2 = num / (gamma * gamma);
                const float mn = sqrtf(fmaxf(m2, 0.f));
                const float arg = fminf(mn, 0.99999f);              // TANH_CLIP
                const float dist = logf((1.f + arg) / (1.f - arg)); // 2*atanh
                logits[(size_t)b * P_SZ + p] = -10.f * dist;        // -dist/TEMP
            }
        }
    }
}

// ---------------------------------------------------------------------------
// Per-row argmax (first-max tie-break) + logmap0(proto[pred]).
// ---------------------------------------------------------------------------
__global__ __launch_bounds__(256) void head_kernel(
    const float* __restrict__ logits, const float* __restrict__ proto,
    float* __restrict__ fb)
{
    const int b = blockIdx.x;
    const int tid = threadIdx.x;

    float best = -INFINITY; int bi = 0;
    for (int p = tid; p < P_SZ; p += 256) {
        const float v = logits[(size_t)b * P_SZ + p];
        if (v > best) { best = v; bi = p; }
    }
    __shared__ float bv[256];
    __shared__ int   bidx[256];
    bv[tid] = best; bidx[tid] = bi;
    __syncthreads();
    for (int s = 128; s; s >>= 1) {
        if (tid < s) {
            const float ov = bv[tid + s]; const int oi = bidx[tid + s];
            if (ov > bv[tid] || (ov == bv[tid] && oi < bidx[tid])) { bv[tid] = ov; bidx[tid] = oi; }
        }
        __syncthreads();
    }
    const int pred = bidx[0];
    __syncthreads();

    float y = 0.f;
    if (tid < 128) y = proto[(size_t)pred * D_SZ + tid];
    bv[tid] = y * y;
    __syncthreads();
    for (int s = 128; s; s >>= 1) {
        if (tid < s) bv[tid] += bv[tid + s];
        __syncthreads();
    }
    const float n2 = bv[0];
    if (tid < 128) {
        const float n = fmaxf(sqrtf(n2), 1e-15f);
        const float arg = fminf(n, 0.99999f);
        const float at = 0.5f * logf((1.f + arg) / (1.f - arg));
        fb[(size_t)b * D_SZ + tid] = at * (y / n);
    }
}

extern "C" void kernel_launch(void* const* d_in, const int* in_sizes, int n_in,
                              void* d_out, int out_size, void* d_ws, size_t ws_size,
                              hipStream_t stream)
{
    const float* x     = (const float*)d_in[0];
    const float* W1    = (const float*)d_in[1];
    const float* b1    = (const float*)d_in[2];
    const float* W2    = (const float*)d_in[3];
    const float* b2v   = (const float*)d_in[4];
    const float* W3    = (const float*)d_in[5];
    const float* b3    = (const float*)d_in[6];
    const float* proto = (const float*)d_in[7];

    float* logits = (float*)d_out;                      // 2048*1000
    float* fb     = logits + (size_t)B_SZ * P_SZ;       // 2048*128

    // workspace layout (bf16 stored as short)
    short* xb    = (short*)d_ws;                         //  2048*1024
    short* w1t   = xb   + (size_t)B_SZ * DIN;            //  4096*1024
    short* w2t   = w1t  + (size_t)H_SZ * DIN;            //  4096*4096
    short* w3t   = w2t  + (size_t)H_SZ * H_SZ;           //   128*4096
    short* h1    = w3t  + (size_t)D_SZ * H_SZ;           //  2048*4096
    short* h2    = h1   + (size_t)B_SZ * H_SZ;           //  2048*4096
    float* u     = (float*)(h2 + (size_t)B_SZ * H_SZ);   //  2048*128 fp32
    float* rowb2 = u + (size_t)B_SZ * D_SZ;              //  2048
    float* a2g   = rowb2 + B_SZ;                         //  1000

    // allow 144KB dynamic LDS for the pipelined GEMM (idempotent, no stream op)
    static_cast<void>(hipFuncSetAttribute(
        reinterpret_cast<const void*>(&gemm_big),
        hipFuncAttributeMaxDynamicSharedMemorySize, 3 * 49152));

    // --- precision prep: bf16 copies (x) and bf16 transposes (W1,W2,W3) ---
    cvt_bf16<<<(B_SZ * DIN) / 1024, 256, 0, stream>>>(x, xb, B_SZ * DIN);
    transpose_bf16<<<dim3(H_SZ / 64, DIN / 64), 256, 0, stream>>>(W1, w1t, DIN, H_SZ);
    transpose_bf16<<<dim3(H_SZ / 64, H_SZ / 64), 256, 0, stream>>>(W2, w2t, H_SZ, H_SZ);
    transpose_bf16<<<dim3(D_SZ / 64, H_SZ / 64), 256, 0, stream>>>(W3, w3t, H_SZ, D_SZ);

    // --- MLP ---
    gemm_big<<<dim3(H_SZ / 128, B_SZ / 256), 512, 3 * 49152, stream>>>(
        xb, w1t, b1, h1, B_SZ, H_SZ, DIN);
    gemm_big<<<dim3(H_SZ / 128, B_SZ / 256), 512, 3 * 49152, stream>>>(
        h1, w2t, b2v, h2, B_SZ, H_SZ, H_SZ);
    hipMemsetAsync(u, 0, (size_t)B_SZ * D_SZ * sizeof(float), stream);
    gemm_small_splitk<<<dim3(1, B_SZ / 128, 8), 256, 0, stream>>>(
        h2, w3t, u, B_SZ, D_SZ, H_SZ);

    // --- hyperbolic head (fp32) ---
    expmap_kernel<<<B_SZ, 128, 0, stream>>>(u, b3, rowb2);
    a2_kernel<<<P_SZ, 128, 0, stream>>>(proto, a2g);
    dist_kernel<<<dim3((P_SZ + 63) / 64, B_SZ / 64), 256, 0, stream>>>(u, proto, rowb2, a2g, logits);
    head_kernel<<<B_SZ, 256, 0, stream>>>(logits, proto, fb);
}

// Round 6
// 271.977 us; speedup vs baseline: 1.1344x; 1.1344x over previous
//
#include <hip/hip_runtime.h>
#include <math.h>

#define B_SZ 2048
#define DIN  1024
#define H_SZ 4096
#define D_SZ 128
#define P_SZ 1000
#define PPAD 1024

typedef __attribute__((ext_vector_type(8))) short bf16x8;
typedef __attribute__((ext_vector_type(4))) float f32x4;

__device__ __forceinline__ float gelu_exact(float v) {
    return 0.5f * v * (1.0f + erff(v * 0.70710678118654752f));
}

__device__ __forceinline__ short f2bf(float f) {
    unsigned u = __float_as_uint(f);
    u = (u + 0x7fffu + ((u >> 16) & 1u)) >> 16;
    return (short)u;
}

// async global->LDS, 16B per lane. LDS dest = wave-uniform base + lane*16.
__device__ __forceinline__ void gload_lds16(const void* g, void* l) {
    __builtin_amdgcn_global_load_lds(
        (__attribute__((address_space(1))) void*)(uintptr_t)g,
        (__attribute__((address_space(3))) void*)(uintptr_t)l,
        16, 0, 0);
}

// ---------------------------------------------------------------------------
// fp32 -> bf16 elementwise
// ---------------------------------------------------------------------------
__global__ __launch_bounds__(256) void cvt_bf16(
    const float* __restrict__ in, short* __restrict__ out, int n)
{
    const int i = (blockIdx.x * 256 + threadIdx.x) * 4;
    if (i + 3 < n) {
        const float4 v = *reinterpret_cast<const float4*>(&in[i]);
        short4 o;
        o.x = f2bf(v.x); o.y = f2bf(v.y); o.z = f2bf(v.z); o.w = f2bf(v.w);
        *reinterpret_cast<short4*>(&out[i]) = o;
    }
}

// ---------------------------------------------------------------------------
// Transpose + convert: W[K][N] fp32 -> WT[N][K] bf16. 64x64 tiles.
// float4 coalesced reads (16B/lane), bf16x8 coalesced writes (16B/lane).
// LDS stride 65 floats: both access patterns max 2-way bank alias (free).
// ---------------------------------------------------------------------------
__global__ __launch_bounds__(256) void transpose_bf16(
    const float* __restrict__ W, short* __restrict__ WT, int K, int N)
{
    __shared__ float t[64][65];
    const int tid = threadIdx.x;
    const int n0 = blockIdx.x * 64, k0 = blockIdx.y * 64;

    #pragma unroll
    for (int i = 0; i < 4; ++i) {
        const int idx = i * 256 + tid;          // float4 index
        const int r  = idx >> 4;                // k-row (16 float4 per row)
        const int c4 = (idx & 15) * 4;
        const float4 v = *reinterpret_cast<const float4*>(&W[(size_t)(k0 + r) * N + n0 + c4]);
        t[r][c4 + 0] = v.x; t[r][c4 + 1] = v.y; t[r][c4 + 2] = v.z; t[r][c4 + 3] = v.w;
    }
    __syncthreads();

    #pragma unroll
    for (int i = 0; i < 2; ++i) {
        const int idx = i * 256 + tid;
        const int n  = idx >> 3;                // 8 k-chunks per n-row
        const int kc = (idx & 7) * 8;
        bf16x8 o;
        #pragma unroll
        for (int q = 0; q < 8; ++q) o[q] = f2bf(t[kc + q][n]);
        *reinterpret_cast<bf16x8*>(&WT[(size_t)(n0 + n) * K + k0 + kc]) = o;
    }
}

// ---------------------------------------------------------------------------
// Prototypes: pad to 1024 rows, convert to bf16, compute a2 (0 for pad rows).
// ---------------------------------------------------------------------------
__global__ __launch_bounds__(128) void proto_prep(
    const float* __restrict__ proto, short* __restrict__ protob,
    float* __restrict__ a2gp)
{
    const int p = blockIdx.x;
    const int d = threadIdx.x;
    const float y = (p < P_SZ) ? proto[(size_t)p * D_SZ + d] : 0.f;
    protob[(size_t)p * D_SZ + d] = f2bf(y);
    float s = y * y;
    #pragma unroll
    for (int off = 32; off; off >>= 1) s += __shfl_down(s, off);
    __shared__ float part[2];
    if ((d & 63) == 0) part[d >> 6] = s;
    __syncthreads();
    if (d == 0) a2gp[p] = part[0] + part[1];
}

// ---------------------------------------------------------------------------
// Big pipelined bf16 MFMA GEMM (round-4 proven structure).
//   A : M x K bf16 row-major;  BT : N x K bf16 row-major (B transposed)
// Tile 256(M) x 128(N), BK=64, 512 threads = 8 waves (4M x 2N), per-wave 64x64.
// 3-deep LDS pipeline, counted vmcnt(6), source-side XOR swizzle (T2 via #21).
// EPI 0: gelu(x+bias) -> bf16. EPI 1: split-K plain store to per-z fp32 slice.
// ---------------------------------------------------------------------------
template<int EPI>
__global__ __launch_bounds__(512) void gemm_big(
    const short* __restrict__ A, const short* __restrict__ BT,
    const float* __restrict__ bias, void* __restrict__ Cout,
    int M, int N, int K)
{
    extern __shared__ __align__(16) char smem[];   // 3 * (32KB A + 16KB B)

    const int tid  = threadIdx.x;
    const int lane = tid & 63;
    const int wid  = tid >> 6;
    const int row0 = blockIdx.y * 256;
    const int col0 = blockIdx.x * 128;
    const int wm = (wid >> 1) * 64;    // wave's 64-row slab
    const int wn = (wid & 1) * 64;     // wave's 64-col slab
    const int lr = lane & 15, kq = lane >> 4;

    const int kpb    = K / gridDim.z;  // split-K chunk
    const int kstart = blockIdx.z * kpb;
    const int NT = kpb >> 6;           // K64 tiles in this chunk

    f32x4 acc[4][4];
    #pragma unroll
    for (int i = 0; i < 4; ++i)
        #pragma unroll
        for (int j = 0; j < 4; ++j) acc[i][j] = (f32x4){0.f, 0.f, 0.f, 0.f};

    // per-lane staging source (pre-swizzled k-chunk)
    const int srow = lane >> 3;              // row within 8-row group
    const int kch  = (lane & 7) ^ srow;      // swizzled 16B k-chunk 0..7
    const short* Ag = A  + (size_t)(row0 + wid * 32 + srow) * K + kstart + kch * 8;
    const short* Bg = BT + (size_t)(col0 + wid * 16 + srow) * K + kstart + kch * 8;

    auto stage = [&](int t) {
        const int buf = t % 3;
        char* sA = smem + buf * 49152;
        char* sB = sA + 32768;
        const int k0 = t << 6;
        #pragma unroll
        for (int ii = 0; ii < 4; ++ii)      // A: 256 rows = 32 instr, 4/wave
            gload_lds16(Ag + (size_t)ii * 8 * K + k0, sA + (wid * 4 + ii) * 1024);
        #pragma unroll
        for (int ii = 0; ii < 2; ++ii)      // B: 128 rows = 16 instr, 2/wave
            gload_lds16(Bg + (size_t)ii * 8 * K + k0, sB + (wid * 2 + ii) * 1024);
    };

    stage(0);
    stage(1);
    asm volatile("s_waitcnt vmcnt(6)" ::: "memory");   // tile 0 resident
    __builtin_amdgcn_s_barrier();
    asm volatile("" ::: "memory");

    for (int t = 0; t < NT; ++t) {
        const bool more = (t + 2) < NT;
        if (more) stage(t + 2);             // uniform branch

        const char* sA = smem + (t % 3) * 49152;
        const char* sB = sA + 32768;

        #pragma unroll
        for (int ks = 0; ks < 2; ++ks) {
            bf16x8 af[4], bfv[4];
            #pragma unroll
            for (int i = 0; i < 4; ++i) {
                const int row = wm + i * 16 + lr;
                af[i] = *reinterpret_cast<const bf16x8*>(
                    sA + row * 128 + (((ks * 4 + kq) ^ (lr & 7)) * 16));
            }
            #pragma unroll
            for (int j = 0; j < 4; ++j) {
                const int row = wn + j * 16 + lr;
                bfv[j] = *reinterpret_cast<const bf16x8*>(
                    sB + row * 128 + (((ks * 4 + kq) ^ (lr & 7)) * 16));
            }
            __builtin_amdgcn_s_setprio(1);
            #pragma unroll
            for (int i = 0; i < 4; ++i)
                #pragma unroll
                for (int j = 0; j < 4; ++j)
                    acc[i][j] = __builtin_amdgcn_mfma_f32_16x16x32_bf16(
                        af[i], bfv[j], acc[i][j], 0, 0, 0);
            __builtin_amdgcn_s_setprio(0);
        }

        asm volatile("" ::: "memory");
        if (more) asm volatile("s_waitcnt vmcnt(6) lgkmcnt(0)" ::: "memory");
        else      asm volatile("s_waitcnt vmcnt(0) lgkmcnt(0)" ::: "memory");
        __builtin_amdgcn_s_barrier();
        asm volatile("" ::: "memory");
    }

    // Epilogue. D frag layout: row = (lane>>4)*4 + q, col = lane&15.
    #pragma unroll
    for (int j = 0; j < 4; ++j) {
        const int col = col0 + wn + j * 16 + lr;
        const float bv = (EPI == 0) ? bias[col] : 0.f;
        #pragma unroll
        for (int i = 0; i < 4; ++i) {
            #pragma unroll
            for (int q = 0; q < 4; ++q) {
                const int row = row0 + wm + i * 16 + kq * 4 + q;
                if (EPI == 0) {
                    float v = gelu_exact(acc[i][j][q] + bv);
                    ((short*)Cout)[(size_t)row * N + col] = f2bf(v);
                } else {
                    ((float*)Cout)[((size_t)blockIdx.z * M + row) * N + col] = acc[i][j][q];
                }
            }
        }
    }
}

// ---------------------------------------------------------------------------
// expmap0: u = sum_z up[z] + b3 -> x_hyp (bf16) ; rowb2 = tanh(||u||)^2.
// ---------------------------------------------------------------------------
__global__ __launch_bounds__(128) void expmap_kernel(
    const float* __restrict__ up, const float* __restrict__ b3,
    short* __restrict__ xhb, float* __restrict__ rowb2)
{
    const int b = blockIdx.x;
    const int d = threadIdx.x;
    float u = b3[d];
    #pragma unroll
    for (int z = 0; z < 16; ++z)
        u += up[((size_t)z * B_SZ + b) * D_SZ + d];

    float s = u * u;
    #pragma unroll
    for (int off = 32; off; off >>= 1) s += __shfl_down(s, off);
    __shared__ float part[2];
    if ((d & 63) == 0) part[d >> 6] = s;
    __syncthreads();
    const float n2 = part[0] + part[1];

    const float n = fmaxf(sqrtf(n2), 1e-15f);
    const float t = tanhf(n);
    xhb[(size_t)b * D_SZ + d] = f2bf(u * (t / n));
    if (d == 0) rowb2[b] = t * t;
}

// ---------------------------------------------------------------------------
// MFMA pairwise hyperbolic distance -> logits.
// Tile 128(b) x 64(p), 256 threads = 4 waves (2b x 2p of 64x32). K = 128.
// Same staging/swizzle discipline as gemm_big extended to 256B rows
// (16 chunks: phys = (c&8) | ((c&7) ^ (row&7))). Epilogue fp32 formula.
// ---------------------------------------------------------------------------
__global__ __launch_bounds__(256) void dist_mfma(
    const short* __restrict__ xhb, const short* __restrict__ protob,
    const float* __restrict__ rowb2, const float* __restrict__ a2gp,
    float* __restrict__ logits)
{
    __shared__ __align__(16) char xs[128 * 256];  // 32 KB [row][256B]
    __shared__ __align__(16) char ps[64 * 256];   // 16 KB

    const int tid  = threadIdx.x;
    const int lane = tid & 63, wid = tid >> 6;
    const int pt = blockIdx.x * 64;
    const int bt = blockIdx.y * 128;
    const int wm = (wid >> 1) * 64;    // b slab
    const int wn = (wid & 1) * 32;     // p slab
    const int lr = lane & 15, kq = lane >> 4;

    // staging: each 1KB gload covers 4 rows x 16 chunks; lane = rl*16 + c
    const int rl = lane >> 4, c = lane & 15;
    #pragma unroll
    for (int i = 0; i < 8; ++i) {          // xh: 32 gloads, 8/wave
        const int row = wid * 32 + i * 4 + rl;
        const int lc  = (c & 8) | ((c & 7) ^ (row & 7));
        gload_lds16(xhb + (size_t)(bt + row) * D_SZ + lc * 8,
                    xs + (wid * 8 + i) * 1024);
    }
    #pragma unroll
    for (int i = 0; i < 4; ++i) {          // proto: 16 gloads, 4/wave
        const int row = wid * 16 + i * 4 + rl;
        const int lc  = (c & 8) | ((c & 7) ^ (row & 7));
        gload_lds16(protob + (size_t)(pt + row) * D_SZ + lc * 8,
                    ps + (wid * 4 + i) * 1024);
    }
    __syncthreads();

    f32x4 acc[4][2];
    #pragma unroll
    for (int i = 0; i < 4; ++i)
        #pragma unroll
        for (int j = 0; j < 2; ++j) acc[i][j] = (f32x4){0.f, 0.f, 0.f, 0.f};

    #pragma unroll
    for (int ks = 0; ks < 4; ++ks) {
        const int kslot = ks * 4 + kq;
        bf16x8 af[4], bfv[2];
        #pragma unroll
        for (int i = 0; i < 4; ++i) {
            const int row = wm + i * 16 + lr;
            const int ph = (kslot & 8) | ((kslot & 7) ^ (row & 7));
            af[i] = *reinterpret_cast<const bf16x8*>(xs + row * 256 + ph * 16);
        }
        #pragma unroll
        for (int j = 0; j < 2; ++j) {
            const int row = wn + j * 16 + lr;
            const int ph = (kslot & 8) | ((kslot & 7) ^ (row & 7));
            bfv[j] = *reinterpret_cast<const bf16x8*>(ps + row * 256 + ph * 16);
        }
        #pragma unroll
        for (int i = 0; i < 4; ++i)
            #pragma unroll
            for (int j = 0; j < 2; ++j)
                acc[i][j] = __builtin_amdgcn_mfma_f32_16x16x32_bf16(
                    af[i], bfv[j], acc[i][j], 0, 0, 0);
    }

    // epilogue: hyperbolic formula, fp32. D frag: row=(lane>>4)*4+q, col=lane&15
    #pragma unroll
    for (int j = 0; j < 2; ++j) {
        const int p = pt + wn + j * 16 + lr;
        if (p < P_SZ) {
            const float a2 = a2gp[p];
            #pragma unroll
            for (int i = 0; i < 4; ++i) {
                #pragma unroll
                for (int q = 0; q < 4; ++q) {
                    const int b = bt + wm + i * 16 + kq * 4 + q;
                    const float b2 = rowb2[b];
                    const float ab = -acc[i][j][q];
                    const float alpha = 1.f + 2.f * ab + b2;
                    const float beta  = 1.f - a2;
                    const float gamma = 1.f + 2.f * ab + a2 * b2;
                    const float num = alpha * alpha * a2 + 2.f * alpha * beta * ab + beta * beta * b2;
                    const float m2 = num / (gamma * gamma);
                    const float mn = sqrtf(fmaxf(m2, 0.f));
                    const float arg = fminf(mn, 0.99999f);              // TANH_CLIP
                    const float dist = logf((1.f + arg) / (1.f - arg)); // 2*atanh
                    logits[(size_t)b * P_SZ + p] = -10.f * dist;        // -dist/TEMP
                }
            }
        }
    }
}

// ---------------------------------------------------------------------------
// Per-row argmax (first-max tie-break) + logmap0(proto[pred]).
// ---------------------------------------------------------------------------
__global__ __launch_bounds__(256) void head_kernel(
    const float* __restrict__ logits, const float* __restrict__ proto,
    float* __restrict__ fb)
{
    const int b = blockIdx.x;
    const int tid = threadIdx.x;

    float best = -INFINITY; int bi = 0;
    for (int p = tid; p < P_SZ; p += 256) {
        const float v = logits[(size_t)b * P_SZ + p];
        if (v > best) { best = v; bi = p; }
    }
    __shared__ float bv[256];
    __shared__ int   bidx[256];
    bv[tid] = best; bidx[tid] = bi;
    __syncthreads();
    for (int s = 128; s; s >>= 1) {
        if (tid < s) {
            const float ov = bv[tid + s]; const int oi = bidx[tid + s];
            if (ov > bv[tid] || (ov == bv[tid] && oi < bidx[tid])) { bv[tid] = ov; bidx[tid] = oi; }
        }
        __syncthreads();
    }
    const int pred = bidx[0];
    __syncthreads();

    float y = 0.f;
    if (tid < 128) y = proto[(size_t)pred * D_SZ + tid];
    bv[tid] = y * y;
    __syncthreads();
    for (int s = 128; s; s >>= 1) {
        if (tid < s) bv[tid] += bv[tid + s];
        __syncthreads();
    }
    const float n2 = bv[0];
    if (tid < 128) {
        const float n = fmaxf(sqrtf(n2), 1e-15f);
        const float arg = fminf(n, 0.99999f);
        const float at = 0.5f * logf((1.f + arg) / (1.f - arg));
        fb[(size_t)b * D_SZ + tid] = at * (y / n);
    }
}

extern "C" void kernel_launch(void* const* d_in, const int* in_sizes, int n_in,
                              void* d_out, int out_size, void* d_ws, size_t ws_size,
                              hipStream_t stream)
{
    const float* x     = (const float*)d_in[0];
    const float* W1    = (const float*)d_in[1];
    const float* b1    = (const float*)d_in[2];
    const float* W2    = (const float*)d_in[3];
    const float* b2v   = (const float*)d_in[4];
    const float* W3    = (const float*)d_in[5];
    const float* b3    = (const float*)d_in[6];
    const float* proto = (const float*)d_in[7];

    float* logits = (float*)d_out;                      // 2048*1000
    float* fb     = logits + (size_t)B_SZ * P_SZ;       // 2048*128

    // workspace layout (bf16 stored as short)
    short* xb     = (short*)d_ws;                        //  2048*1024
    short* w1t    = xb    + (size_t)B_SZ * DIN;          //  4096*1024
    short* w2t    = w1t   + (size_t)H_SZ * DIN;          //  4096*4096
    short* w3t    = w2t   + (size_t)H_SZ * H_SZ;         //   128*4096
    short* h1     = w3t   + (size_t)D_SZ * H_SZ;         //  2048*4096 (bf16)
    short* h2     = h1    + (size_t)B_SZ * H_SZ;         //  2048*4096
    short* xhb    = h2    + (size_t)B_SZ * H_SZ;         //  2048*128 bf16
    short* protob = xhb   + (size_t)B_SZ * D_SZ;         //  1024*128 bf16
    float* rowb2  = (float*)(protob + (size_t)PPAD * D_SZ); // 2048 fp32
    float* a2gp   = rowb2 + B_SZ;                        //  1024 fp32
    // up aliases h1 (dead after GEMM2): 16 slices * 2048*128 fp32 = 16 MB
    float* up     = (float*)h1;

    static_cast<void>(hipFuncSetAttribute(
        reinterpret_cast<const void*>(&gemm_big<0>),
        hipFuncAttributeMaxDynamicSharedMemorySize, 3 * 49152));
    static_cast<void>(hipFuncSetAttribute(
        reinterpret_cast<const void*>(&gemm_big<1>),
        hipFuncAttributeMaxDynamicSharedMemorySize, 3 * 49152));

    // --- precision prep ---
    cvt_bf16<<<(B_SZ * DIN) / 1024, 256, 0, stream>>>(x, xb, B_SZ * DIN);
    transpose_bf16<<<dim3(H_SZ / 64, DIN / 64), 256, 0, stream>>>(W1, w1t, DIN, H_SZ);
    transpose_bf16<<<dim3(H_SZ / 64, H_SZ / 64), 256, 0, stream>>>(W2, w2t, H_SZ, H_SZ);
    transpose_bf16<<<dim3(D_SZ / 64, H_SZ / 64), 256, 0, stream>>>(W3, w3t, H_SZ, D_SZ);
    proto_prep<<<PPAD, 128, 0, stream>>>(proto, protob, a2gp);

    // --- MLP ---
    gemm_big<0><<<dim3(H_SZ / 128, B_SZ / 256), 512, 3 * 49152, stream>>>(
        xb, w1t, b1, h1, B_SZ, H_SZ, DIN);
    gemm_big<0><<<dim3(H_SZ / 128, B_SZ / 256), 512, 3 * 49152, stream>>>(
        h1, w2t, b2v, h2, B_SZ, H_SZ, H_SZ);
    // GEMM3: split-K=16, per-z slices (no atomics); up aliases h1 (h1 dead now)
    gemm_big<1><<<dim3(1, B_SZ / 256, 16), 512, 3 * 49152, stream>>>(
        h2, w3t, nullptr, up, B_SZ, D_SZ, H_SZ);

    // --- hyperbolic head ---
    expmap_kernel<<<B_SZ, 128, 0, stream>>>(up, b3, xhb, rowb2);
    dist_mfma<<<dim3(PPAD / 64, B_SZ / 128), 256, 0, stream>>>(
        xhb, protob, rowb2, a2gp, logits);
    head_kernel<<<B_SZ, 256, 0, stream>>>(logits, proto, fb);
}